// Round 20
// baseline (37.196 us; speedup 1.0000x reference)
//
#include <hip/hip_runtime.h>
#include <math.h>

#define WIN 16       // hard cap: adaptive window within +/-16 (R13/R17-verified)
#define THRESH 20.0f // keep indices with score >= m - THRESH (e^-20 truncation)
#define FPW 8        // frames per wave
#define NW  8        // waves per block
#define FPB (FPW * NW)   // 64 frames per block
#define CH  16       // staged rows per chunk (32 KB)

#define AS1 __attribute__((address_space(1)))
#define AS3 __attribute__((address_space(3)))

// Fused prep (verbatim R19, verified): per-(batch, 256-frame chunk) block:
// double-precision Hillis-Steele scan in LDS (bit-identical centers),
// adaptive bounds vs LDS, pm = {asfloat(a|K<<16), m, inv, 0}; chunk 0
// writes c.
__global__ __launch_bounds__(256) void prep_kernel(
    const float* __restrict__ dur, const int* __restrict__ lens,
    float* __restrict__ c, float4* __restrict__ pm, int N, int T) {
    __shared__ double s[512];
    __shared__ float cf[512];
    int tpc = T >> 8;
    int b   = blockIdx.x / tpc;
    int tc  = blockIdx.x - b * tpc;
    int tid = threadIdx.x;

    int n0 = tid, n1 = tid + 256;
    float d0 = dur[(size_t)b * N + n0];
    float d1 = dur[(size_t)b * N + n1];
    s[n0] = (double)d0; s[n1] = (double)d1;
    __syncthreads();
    for (int off = 1; off < N; off <<= 1) {
        double v0 = (n0 >= off) ? s[n0 - off] : 0.0;
        double v1 = (n1 >= off) ? s[n1 - off] : 0.0;
        __syncthreads();
        s[n0] += v0; s[n1] += v1;
        __syncthreads();
    }
    cf[n0] = (float)(s[n0] - 0.5 * (double)d0);
    cf[n1] = (float)(s[n1] - 0.5 * (double)d1);
    __syncthreads();
    if (tc == 0) {
        c[(size_t)b * N + n0] = cf[n0];
        c[(size_t)b * N + n1] = cf[n1];
    }

    int L = lens[b];
    if (L < 1) L = 1;
    if (L > N) L = N;
    int t = tc * 256 + tid;
    float tf = (float)t;
    int lo = 0, hi = L;
    while (lo < hi) {
        int mid = (lo + hi) >> 1;
        if (cf[mid] < tf) lo = mid + 1; else hi = mid;
    }
    int j = lo;
    if (j >= L) j = L - 1;
    float cj   = cf[j];
    float cjm1 = cf[(j > 0) ? (j - 1) : 0];
    if (j > 0 && (tf - cjm1) < (cj - tf)) j--;
    float dm = tf - cf[j];
    float m = -0.5f * dm * dm;
    float lim = m - THRESH;
    int aCap = j - WIN; if (aCap < 0) aCap = 0;
    int eCap = j + WIN; if (eCap > L - 1) eCap = L - 1;
    int a = j, e = j;
    while (a > aCap) {
        float d = tf - cf[a - 1];
        if (-0.5f * d * d >= lim) --a; else break;
    }
    while (e < eCap) {
        float d = tf - cf[e + 1];
        if (-0.5f * d * d >= lim) ++e; else break;
    }
    float sum = 0.0f;
    for (int k = a; k <= e; ++k) {
        float d = tf - cf[k];
        sum += __expf(-0.5f * d * d - m);
    }
    float4 o;
    o.x = __uint_as_float((unsigned)(a | ((e - a + 1) << 16)));
    o.y = m;
    o.z = 1.0f / sum;
    o.w = 0.0f;
    pm[(size_t)b * T + t] = o;
}

// Main kernel: verbatim R19 math/structure, widened to 8 waves x 8 frames
// (512 threads, 64 frames/block): staged rows shared by 2x the frames,
// per-block prologue/barrier overhead amortized 2x. Same wave/CU count.
__global__ __launch_bounds__(512, 2) void upsample_rl(
    const float* __restrict__ x,    // [B,N,H]
    const float* __restrict__ c,    // [B,N]
    const float4* __restrict__ pm,  // [B,T] {asfloat(a|K<<16), m, inv, -}
    float* __restrict__ out,        // [B,T,H]
    int B, int N, int H, int T) {
    __shared__ float rows[CH][512];        // 32 KB staged input rows (H=512)
    __shared__ int   bmin[NW], bmax[NW];   // per-wave window extremes

    int nwg = gridDim.x;
    int bid = blockIdx.x;
    if ((nwg & 7) == 0) {                  // XCD-bijective swizzle
        int cpx = nwg >> 3;
        bid = (bid & 7) * cpx + (bid >> 3);
    }
    int wave = threadIdx.x >> 6;
    int lane = threadIdx.x & 63;

    int tilesPerB = T / FPB;
    int b   = bid / tilesPerB;
    int t0  = (bid - b * tilesPerB) * FPB + wave * FPW;

    const float* cb = c + (size_t)b * N;

    // ---- per-frame window params: one packed float4 per frame ----
    const float4* pmb = pm + (size_t)b * T + t0;
    float tf[FPW], m_[FPW], iv[FPW];
    int a[FPW], K[FPW];
    int amin = 0x7fffffff, emax = 0;
    #pragma unroll
    for (int f = 0; f < FPW; ++f) {
        tf[f] = (float)(t0 + f);
        float4 p = pmb[f];
        unsigned pk = __float_as_uint(p.x);
        a[f] = (int)(pk & 0xffffu);
        K[f] = (int)(pk >> 16);
        m_[f] = p.y;
        iv[f] = p.z;
        int ef = a[f] + K[f] - 1;
        if (a[f] < amin) amin = a[f];
        if (ef > emax)   emax = ef;
    }

    // ---- block union window: explicit min/max across the 8 waves ----
    if (lane == 0) { bmin[wave] = amin; bmax[wave] = emax; }
    __syncthreads();
    int n0 = bmin[0], ne = bmax[0];
    #pragma unroll
    for (int wv = 1; wv < NW; ++wv) {
        n0 = min(n0, bmin[wv]);
        ne = max(ne, bmax[wv]);
    }
    int span = ne - n0 + 1;

    const float* gbase = x + ((size_t)b * N + n0) * (size_t)H;

    float4 acc[FPW][2];
    #pragma unroll
    for (int f = 0; f < FPW; ++f) {
        acc[f][0] = make_float4(0.f, 0.f, 0.f, 0.f);
        acc[f][1] = make_float4(0.f, 0.f, 0.f, 0.f);
    }

    for (int kb = 0; kb < span; kb += CH) {
        int klen = span - kb; if (klen > CH) klen = CH;

        // ---- async stage (verbatim): linear dest == linear read ----
        for (int r = wave; r < klen; r += NW) {
            const char* g = (const char*)(gbase + (size_t)(kb + r) * H);
            __builtin_amdgcn_global_load_lds(
                (const AS1 void*)(g + lane * 16),
                (AS3 void*)&rows[r][0], 16, 0, 0);
            __builtin_amdgcn_global_load_lds(
                (const AS1 void*)(g + 1024 + lane * 16),
                (AS3 void*)&rows[r][256], 16, 0, 0);
        }

        // ---- per-lane weights (verbatim expression; overlaps DMA) ----
        int nidx = n0 + kb + lane;
        int ci = nidx; if (ci > N - 1) ci = N - 1;
        float cv = cb[ci];
        float wv[FPW];
        #pragma unroll
        for (int f = 0; f < FPW; ++f) {
            float d  = tf[f] - cv;
            float wval = __expf(-0.5f * d * d - m_[f]) * iv[f];
            unsigned q = (unsigned)(nidx - a[f]);
            wv[f] = (q < (unsigned)K[f]) ? wval : 0.0f;
        }
        __syncthreads();                   // DMA drained; rows resident

        // ---- fma from LDS, ascending k; readlane broadcast (verbatim) ----
        for (int k = 0; k < klen; ++k) {
            float wk[FPW];
            #pragma unroll
            for (int f = 0; f < FPW; ++f)
                wk[f] = __uint_as_float(
                    __builtin_amdgcn_readlane(__float_as_uint(wv[f]), k));
            const float4* row = (const float4*)rows[k];
            float4 va = row[lane];
            float4 vb = row[64 + lane];
            #pragma unroll
            for (int f = 0; f < FPW; ++f) {
                acc[f][0].x = fmaf(wk[f], va.x, acc[f][0].x);
                acc[f][0].y = fmaf(wk[f], va.y, acc[f][0].y);
                acc[f][0].z = fmaf(wk[f], va.z, acc[f][0].z);
                acc[f][0].w = fmaf(wk[f], va.w, acc[f][0].w);
                acc[f][1].x = fmaf(wk[f], vb.x, acc[f][1].x);
                acc[f][1].y = fmaf(wk[f], vb.y, acc[f][1].y);
                acc[f][1].z = fmaf(wk[f], vb.z, acc[f][1].z);
                acc[f][1].w = fmaf(wk[f], vb.w, acc[f][1].w);
            }
        }
        __syncthreads();                   // rows safe to overwrite
    }

    // ---- store the wave's 8 frames ----
    float* obase = out + ((size_t)b * T + t0) * (size_t)H;
    #pragma unroll
    for (int f = 0; f < FPW; ++f) {
        float4* o = (float4*)(obase + (size_t)f * H);
        o[lane]      = acc[f][0];
        o[64 + lane] = acc[f][1];
    }
}

extern "C" void kernel_launch(void* const* d_in, const int* in_sizes, int n_in,
                              void* d_out, int out_size, void* d_ws, size_t ws_size,
                              hipStream_t stream) {
    const float* x    = (const float*)d_in[0];  // [B,N,H] f32
    const int*   lens = (const int*)d_in[1];    // [B] int
    const float* dur  = (const float*)d_in[2];  // [B,N] f32

    int B  = in_sizes[1];
    int BN = in_sizes[2];
    int N  = BN / B;
    int H  = in_sizes[0] / BN;
    int T  = out_size / (B * H);

    size_t cB = (size_t)B * N * sizeof(float);
    cB = (cB + 15) & ~(size_t)15;               // align pm to 16B

    float*  c  = (float*)d_ws;
    float4* pm = (float4*)((char*)d_ws + cB);   // B*T float4 (4 MB)

    prep_kernel<<<B * (T >> 8), 256, 0, stream>>>(dur, lens, c, pm, N, T);

    int blocks = (B * T) / FPB;                 // 64 frames per block
    upsample_rl<<<blocks, 512, 0, stream>>>(x, c, pm, (float*)d_out,
                                            B, N, H, T);
}

// Round 21
// 35.721 us; speedup vs baseline: 1.0413x; 1.0413x over previous
//
#include <hip/hip_runtime.h>
#include <math.h>

#define WIN 16       // hard cap: adaptive window within +/-16 (R13/R17-verified)
#define THRESH 20.0f // keep indices with score >= m - THRESH (e^-20 truncation)
#define FPW 8        // frames per wave
#define NW  4        // waves per block
#define FPB (FPW * NW)   // 32 frames per block
#define CH  16       // staged rows per chunk (32 KB)

#define AS1 __attribute__((address_space(1)))
#define AS3 __attribute__((address_space(3)))

// Fused prep (verified R19): one block = (batch b, 256-frame chunk).
// Double-precision Hillis-Steele scan in LDS (bit-identical centers to the
// original centers_kernel), then the verified adaptive-bounds code against
// LDS. Emits pm = {asfloat(a|K<<16), m, inv, 0}; chunk 0 writes c.
__global__ __launch_bounds__(256) void prep_kernel(
    const float* __restrict__ dur, const int* __restrict__ lens,
    float* __restrict__ c, float4* __restrict__ pm, int N, int T) {
    __shared__ double s[512];
    __shared__ float cf[512];
    int tpc = T >> 8;                      // 256-frame chunks per batch
    int b   = blockIdx.x / tpc;
    int tc  = blockIdx.x - b * tpc;
    int tid = threadIdx.x;

    int n0 = tid, n1 = tid + 256;          // two scan elements per thread
    float d0 = dur[(size_t)b * N + n0];
    float d1 = dur[(size_t)b * N + n1];
    s[n0] = (double)d0; s[n1] = (double)d1;
    __syncthreads();
    for (int off = 1; off < N; off <<= 1) {
        double v0 = (n0 >= off) ? s[n0 - off] : 0.0;
        double v1 = (n1 >= off) ? s[n1 - off] : 0.0;
        __syncthreads();
        s[n0] += v0; s[n1] += v1;
        __syncthreads();
    }
    cf[n0] = (float)(s[n0] - 0.5 * (double)d0);
    cf[n1] = (float)(s[n1] - 0.5 * (double)d1);
    __syncthreads();
    if (tc == 0) {                         // write centers once per batch
        c[(size_t)b * N + n0] = cf[n0];
        c[(size_t)b * N + n1] = cf[n1];
    }

    int L = lens[b];
    if (L < 1) L = 1;
    if (L > N) L = N;
    int t = tc * 256 + tid;
    float tf = (float)t;
    int lo = 0, hi = L;
    while (lo < hi) {
        int mid = (lo + hi) >> 1;
        if (cf[mid] < tf) lo = mid + 1; else hi = mid;
    }
    int j = lo;
    if (j >= L) j = L - 1;
    float cj   = cf[j];
    float cjm1 = cf[(j > 0) ? (j - 1) : 0];
    if (j > 0 && (tf - cjm1) < (cj - tf)) j--;
    float dm = tf - cf[j];
    float m = -0.5f * dm * dm;             // max of windowed scores
    float lim = m - THRESH;
    int aCap = j - WIN; if (aCap < 0) aCap = 0;
    int eCap = j + WIN; if (eCap > L - 1) eCap = L - 1;
    int a = j, e = j;
    while (a > aCap) {
        float d = tf - cf[a - 1];
        if (-0.5f * d * d >= lim) --a; else break;
    }
    while (e < eCap) {
        float d = tf - cf[e + 1];
        if (-0.5f * d * d >= lim) ++e; else break;
    }
    float sum = 0.0f;
    for (int k = a; k <= e; ++k) {
        float d = tf - cf[k];
        sum += __expf(-0.5f * d * d - m);
    }
    float4 o;
    o.x = __uint_as_float((unsigned)(a | ((e - a + 1) << 16)));
    o.y = m;
    o.z = 1.0f / sum;
    o.w = 0.0f;
    pm[(size_t)b * T + t] = o;
}

// Main kernel (verified R19, 35.2us / absmax 0.015625): 4 waves x 8 frames,
// adaptive block-union window staged via global_load_lds (CH=16), per-lane
// weights recomputed from c/m/inv (verbatim expression), readlane broadcast,
// ascending-k fma, coalesced float4 stores.
__global__ __launch_bounds__(256, 4) void upsample_rl(
    const float* __restrict__ x,    // [B,N,H]
    const float* __restrict__ c,    // [B,N]
    const float4* __restrict__ pm,  // [B,T] {asfloat(a|K<<16), m, inv, -}
    float* __restrict__ out,        // [B,T,H]
    int B, int N, int H, int T) {
    __shared__ float rows[CH][512];        // 32 KB staged input rows (H=512)
    __shared__ int   bmin[NW], bmax[NW];   // per-wave window extremes

    int nwg = gridDim.x;
    int bid = blockIdx.x;
    if ((nwg & 7) == 0) {                  // XCD-bijective swizzle
        int cpx = nwg >> 3;
        bid = (bid & 7) * cpx + (bid >> 3);
    }
    int wave = threadIdx.x >> 6;
    int lane = threadIdx.x & 63;

    int tilesPerB = T / FPB;
    int b   = bid / tilesPerB;
    int t0  = (bid - b * tilesPerB) * FPB + wave * FPW;

    const float* cb = c + (size_t)b * N;

    // ---- per-frame window params: one packed float4 per frame ----
    const float4* pmb = pm + (size_t)b * T + t0;
    float tf[FPW], m_[FPW], iv[FPW];
    int a[FPW], K[FPW];
    int amin = 0x7fffffff, emax = 0;
    #pragma unroll
    for (int f = 0; f < FPW; ++f) {
        tf[f] = (float)(t0 + f);
        float4 p = pmb[f];
        unsigned pk = __float_as_uint(p.x);
        a[f] = (int)(pk & 0xffffu);
        K[f] = (int)(pk >> 16);
        m_[f] = p.y;
        iv[f] = p.z;
        int ef = a[f] + K[f] - 1;
        if (a[f] < amin) amin = a[f];
        if (ef > emax)   emax = ef;
    }

    // ---- block union window: explicit min/max across the 4 waves ----
    if (lane == 0) { bmin[wave] = amin; bmax[wave] = emax; }
    __syncthreads();
    int n0 = min(min(bmin[0], bmin[1]), min(bmin[2], bmin[3]));
    int ne = max(max(bmax[0], bmax[1]), max(bmax[2], bmax[3]));
    int span = ne - n0 + 1;

    const float* gbase = x + ((size_t)b * N + n0) * (size_t)H;

    float4 acc[FPW][2];
    #pragma unroll
    for (int f = 0; f < FPW; ++f) {
        acc[f][0] = make_float4(0.f, 0.f, 0.f, 0.f);
        acc[f][1] = make_float4(0.f, 0.f, 0.f, 0.f);
    }

    for (int kb = 0; kb < span; kb += CH) {
        int klen = span - kb; if (klen > CH) klen = CH;

        // ---- async stage (verbatim): linear dest == linear read ----
        for (int r = wave; r < klen; r += NW) {
            const char* g = (const char*)(gbase + (size_t)(kb + r) * H);
            __builtin_amdgcn_global_load_lds(
                (const AS1 void*)(g + lane * 16),
                (AS3 void*)&rows[r][0], 16, 0, 0);
            __builtin_amdgcn_global_load_lds(
                (const AS1 void*)(g + 1024 + lane * 16),
                (AS3 void*)&rows[r][256], 16, 0, 0);
        }

        // ---- per-lane weights (verbatim expression; overlaps DMA) ----
        int nidx = n0 + kb + lane;
        int ci = nidx; if (ci > N - 1) ci = N - 1;
        float cv = cb[ci];
        float wv[FPW];
        #pragma unroll
        for (int f = 0; f < FPW; ++f) {
            float d  = tf[f] - cv;
            float wval = __expf(-0.5f * d * d - m_[f]) * iv[f];
            unsigned q = (unsigned)(nidx - a[f]);
            wv[f] = (q < (unsigned)K[f]) ? wval : 0.0f;
        }
        __syncthreads();                   // DMA drained; rows resident

        // ---- fma from LDS, ascending k; readlane broadcast (verbatim) ----
        for (int k = 0; k < klen; ++k) {
            float wk[FPW];
            #pragma unroll
            for (int f = 0; f < FPW; ++f)
                wk[f] = __uint_as_float(
                    __builtin_amdgcn_readlane(__float_as_uint(wv[f]), k));
            const float4* row = (const float4*)rows[k];
            float4 va = row[lane];
            float4 vb = row[64 + lane];
            #pragma unroll
            for (int f = 0; f < FPW; ++f) {
                acc[f][0].x = fmaf(wk[f], va.x, acc[f][0].x);
                acc[f][0].y = fmaf(wk[f], va.y, acc[f][0].y);
                acc[f][0].z = fmaf(wk[f], va.z, acc[f][0].z);
                acc[f][0].w = fmaf(wk[f], va.w, acc[f][0].w);
                acc[f][1].x = fmaf(wk[f], vb.x, acc[f][1].x);
                acc[f][1].y = fmaf(wk[f], vb.y, acc[f][1].y);
                acc[f][1].z = fmaf(wk[f], vb.z, acc[f][1].z);
                acc[f][1].w = fmaf(wk[f], vb.w, acc[f][1].w);
            }
        }
        __syncthreads();                   // rows safe to overwrite
    }

    // ---- store the wave's 8 frames ----
    float* obase = out + ((size_t)b * T + t0) * (size_t)H;
    #pragma unroll
    for (int f = 0; f < FPW; ++f) {
        float4* o = (float4*)(obase + (size_t)f * H);
        o[lane]      = acc[f][0];
        o[64 + lane] = acc[f][1];
    }
}

extern "C" void kernel_launch(void* const* d_in, const int* in_sizes, int n_in,
                              void* d_out, int out_size, void* d_ws, size_t ws_size,
                              hipStream_t stream) {
    const float* x    = (const float*)d_in[0];  // [B,N,H] f32
    const int*   lens = (const int*)d_in[1];    // [B] int
    const float* dur  = (const float*)d_in[2];  // [B,N] f32

    int B  = in_sizes[1];
    int BN = in_sizes[2];
    int N  = BN / B;
    int H  = in_sizes[0] / BN;
    int T  = out_size / (B * H);

    size_t cB = (size_t)B * N * sizeof(float);
    cB = (cB + 15) & ~(size_t)15;               // align pm to 16B

    float*  c  = (float*)d_ws;
    float4* pm = (float4*)((char*)d_ws + cB);   // B*T float4 (4 MB)

    prep_kernel<<<B * (T >> 8), 256, 0, stream>>>(dur, lens, c, pm, N, T);

    int blocks = (B * T) / FPB;                 // 32 frames per block
    upsample_rl<<<blocks, 256, 0, stream>>>(x, c, pm, (float*)d_out,
                                            B, N, H, T);
}